// Round 3
// baseline (11015.252 us; speedup 1.0000x reference)
//
#include <hip/hip_runtime.h>
#include <cstddef>
#include <cstdint>

// LSTM T=512 B=64 D=1024 H=1024.
//   Phase 1: xg = x @ Wx^T + bh -> bf16 (MFMA 128x128 tile GEMM, reg-staged f32->bf16)
//   Phase 2: ONE persistent kernel, 256 blocks x 1 wave (1 block/CU), 512 steps
//            with a device-scope arrive/spin barrier per step.
//            Wh slice (128 KiB) in LDS per block; c in VGPRs; h via global ping-pong.
// d_out = [outputs(T,B,H) | h(B,H) | c(B,H)] f32.

#define T_DIM 512
#define B_DIM 64
#define H_DIM 1024
#define G_DIM 4096
#define NBLK 256

typedef short short8 __attribute__((ext_vector_type(8)));
typedef float f32x4 __attribute__((ext_vector_type(4)));
typedef unsigned short ushort_t;

__device__ __forceinline__ ushort_t f2b(float f) {   // f32 -> bf16 RNE
  union { float f; unsigned u; } v; v.f = f;
  unsigned r = v.u + 0x7fffu + ((v.u >> 16) & 1u);
  return (ushort_t)(r >> 16);
}
__device__ __forceinline__ float b2f(ushort_t u) {
  union { unsigned u; float f; } v; v.u = ((unsigned)u) << 16;
  return v.f;
}
__device__ __forceinline__ float sigmoidf_(float x) { return 1.0f / (1.0f + __expf(-x)); }

// ---------------------------------------------------------------------------
__global__ __launch_bounds__(256) void reset_bar_kernel(int* __restrict__ bar) {
  int i = blockIdx.x * 256 + threadIdx.x;
  if (i < T_DIM) bar[i] = 0;
}

// convert f32 -> bf16 (Wh), 8 elems/thread
__global__ __launch_bounds__(256) void convert_bf16_kernel(
    const float* __restrict__ src, ushort_t* __restrict__ dst, int n8) {
  int i = blockIdx.x * 256 + threadIdx.x;
  if (i >= n8) return;
  float4 v0 = *(const float4*)&src[(size_t)i * 8];
  float4 v1 = *(const float4*)&src[(size_t)i * 8 + 4];
  ushort_t p[8] = {f2b(v0.x), f2b(v0.y), f2b(v0.z), f2b(v0.w),
                   f2b(v1.x), f2b(v1.y), f2b(v1.z), f2b(v1.w)};
  *(short8*)&dst[(size_t)i * 8] = *(const short8*)p;
}

// ---------------------------------------------------------------------------
// MFMA GEMM (unchanged from round 2): C[m][n] = bf16(sum_k x[m][k]*Wx[n][k] + bh[n])
__global__ __launch_bounds__(256) void xg_gemm_mfma(
    const float* __restrict__ A, const float* __restrict__ Bw,
    const float* __restrict__ bh, ushort_t* __restrict__ C) {
  __shared__ ushort_t As[128 * 64];
  __shared__ ushort_t Bs[128 * 64];
  const int tid = threadIdx.x;
  const int lane = tid & 63;
  const int w = tid >> 6;
  const int wm = w >> 1, wn = w & 1;
  const size_t m0 = (size_t)blockIdx.x * 128;
  const int n0 = blockIdx.y * 128;
  const int r = tid >> 1;
  const int kb = (tid & 1) * 32;

  f32x4 acc[4][4];
#pragma unroll
  for (int i = 0; i < 4; ++i)
#pragma unroll
    for (int j = 0; j < 4; ++j) acc[i][j] = 0.0f;

  const int lr = lane & 15;
  const int lk = (lane >> 4) * 8;

  for (int k0 = 0; k0 < 1024; k0 += 64) {
    __syncthreads();
#pragma unroll
    for (int i = 0; i < 4; ++i) {
      const int kk = kb + i * 8;
      float4 a0 = *(const float4*)&A[(m0 + r) * 1024 + k0 + kk];
      float4 a1 = *(const float4*)&A[(m0 + r) * 1024 + k0 + kk + 4];
      ushort_t pa[8] = {f2b(a0.x), f2b(a0.y), f2b(a0.z), f2b(a0.w),
                        f2b(a1.x), f2b(a1.y), f2b(a1.z), f2b(a1.w)};
      float4 b0 = *(const float4*)&Bw[(size_t)(n0 + r) * 1024 + k0 + kk];
      float4 b1 = *(const float4*)&Bw[(size_t)(n0 + r) * 1024 + k0 + kk + 4];
      ushort_t pb[8] = {f2b(b0.x), f2b(b0.y), f2b(b0.z), f2b(b0.w),
                        f2b(b1.x), f2b(b1.y), f2b(b1.z), f2b(b1.w)};
      const int byte = (r * 128 + kk * 2) ^ ((r & 7) << 4);
      *(short8*)((char*)As + byte) = *(const short8*)pa;
      *(short8*)((char*)Bs + byte) = *(const short8*)pb;
    }
    __syncthreads();
#pragma unroll
    for (int kk = 0; kk < 64; kk += 32) {
      short8 af[4], bf[4];
#pragma unroll
      for (int mf = 0; mf < 4; ++mf) {
        const int row = wm * 64 + mf * 16 + lr;
        const int byte = (row * 128 + (kk + lk) * 2) ^ ((row & 7) << 4);
        af[mf] = *(const short8*)((const char*)As + byte);
      }
#pragma unroll
      for (int nf = 0; nf < 4; ++nf) {
        const int row = wn * 64 + nf * 16 + lr;
        const int byte = (row * 128 + (kk + lk) * 2) ^ ((row & 7) << 4);
        bf[nf] = *(const short8*)((const char*)Bs + byte);
      }
#pragma unroll
      for (int mf = 0; mf < 4; ++mf)
#pragma unroll
        for (int nf = 0; nf < 4; ++nf)
          acc[mf][nf] = __builtin_amdgcn_mfma_f32_16x16x32_bf16(
              af[mf], bf[nf], acc[mf][nf], 0, 0, 0);
    }
  }
#pragma unroll
  for (int nf = 0; nf < 4; ++nf) {
    const int col = n0 + wn * 64 + nf * 16 + lr;
    const float bias = bh[col];
#pragma unroll
    for (int mf = 0; mf < 4; ++mf) {
      const size_t row0 = m0 + wm * 64 + mf * 16 + (lane >> 4) * 4;
#pragma unroll
      for (int rr = 0; rr < 4; ++rr)
        C[(row0 + rr) * 4096 + col] = f2b(acc[mf][nf][rr] + bias);
    }
  }
}

// ---------------------------------------------------------------------------
// Persistent recurrence. 256 blocks x 64 threads, dynamic LDS 128 KiB.
// Block b: j0=(b>>2)*16, w=b&3 (batch quarter). Wave computes 16 j x 4 gates x
// 16 batches per step. Wh rows (4 gates x 16 j) LDS-resident, XOR-swizzled.
// Step barrier: release fence + atomicAdd(bar[t]); spin agent-load; acquire fence.
__global__ __launch_bounds__(64) void lstm_persistent(
    const ushort_t* __restrict__ xg,   // [T*64][4096] bf16 (bias folded)
    const ushort_t* __restrict__ Whb,  // [4096][1024] bf16
    ushort_t* __restrict__ hb0,        // [64][1024] bf16 ping
    ushort_t* __restrict__ hb1,        // [64][1024] bf16 pong
    int* __restrict__ bar,             // [T] arrive counters (zeroed)
    float* __restrict__ out) {         // [T][64][1024] f32 + tail
  extern __shared__ ushort_t Wlds[];   // 64 rows x 1024 bf16 = 128 KiB
  const int lane = threadIdx.x;
  const int j0 = ((int)blockIdx.x >> 2) * 16;
  const int w  = (int)blockIdx.x & 3;
  const int lr = lane & 15;
  const int lq = lane >> 4;            // 0..3
  const int j  = j0 + lr;
  const int rb = w * 16 + lq * 4;      // epilogue batch base
  const int ko = lq * 8;               // A-frag k offset (elements)

  // one-time: stage this block's Wh slice into LDS (swizzled)
  for (int e = lane; e < 8192; e += 64) {
    const int r  = e >> 7;             // LDS row 0..63 (= gate*16 + jj)
    const int ch = e & 127;            // 16B chunk within row
    const int gr = (r >> 4) * 1024 + j0 + (r & 15);
    short8 v = *(const short8*)(Whb + (size_t)gr * 1024 + ch * 8);
    const int byte = (r * 2048 + ch * 16) ^ ((r & 7) << 4);
    *(short8*)((char*)Wlds + byte) = v;
  }

  float creg[4] = {0.f, 0.f, 0.f, 0.f};
  float hv[4];

  for (int t = 0; t < T_DIM; ++t) {
    // prefetch xg[t] (independent of h) before the spin
    float xgv[4][4];
#pragma unroll
    for (int rr = 0; rr < 4; ++rr) {
      const size_t base = ((size_t)t * 64 + rb + rr) * 4096 + j;
#pragma unroll
      for (int g = 0; g < 4; ++g) xgv[g][rr] = b2f(xg[base + (size_t)g * 1024]);
    }

    f32x4 acc[4];
#pragma unroll
    for (int g = 0; g < 4; ++g) acc[g] = 0.f;

    if (t > 0) {
      while (__hip_atomic_load(&bar[t - 1], __ATOMIC_RELAXED,
                               __HIP_MEMORY_SCOPE_AGENT) < NBLK)
        __builtin_amdgcn_s_sleep(1);
      __builtin_amdgcn_fence(__ATOMIC_ACQUIRE, "agent");  // inv stale L1/L2
      const ushort_t* __restrict__ hprev = (t & 1) ? hb0 : hb1;
      const ushort_t* __restrict__ hrow =
          hprev + (size_t)(w * 16 + lr) * 1024 + ko;
      short8 af[32];
#pragma unroll 8
      for (int ks = 0; ks < 32; ++ks)
        af[ks] = *(const short8*)(hrow + ks * 32);
#pragma unroll 8
      for (int ks = 0; ks < 32; ++ks) {
#pragma unroll
        for (int g = 0; g < 4; ++g) {
          const int row = g * 16 + lr;
          const int byte = (row * 2048 + ks * 64 + lq * 16) ^ ((row & 7) << 4);
          short8 bfrag = *(const short8*)((const char*)Wlds + byte);
          acc[g] = __builtin_amdgcn_mfma_f32_16x16x32_bf16(af[ks], bfrag,
                                                           acc[g], 0, 0, 0);
        }
      }
    }

    ushort_t* __restrict__ hcur = (t & 1) ? hb1 : hb0;
#pragma unroll
    for (int rr = 0; rr < 4; ++rr) {
      const int b = rb + rr;
      const float ig = sigmoidf_(acc[0][rr] + xgv[0][rr]);
      const float fg = sigmoidf_(acc[1][rr] + xgv[1][rr]);
      const float gg = tanhf(acc[2][rr] + xgv[2][rr]);
      const float og = sigmoidf_(acc[3][rr] + xgv[3][rr]);
      const float cn = fmaf(fg, creg[rr], ig * gg);
      creg[rr] = cn;
      const float h = og * tanhf(cn);
      hv[rr] = h;
      out[((size_t)t * 64 + b) * 1024 + j] = h;
      hcur[(size_t)b * 1024 + j] = f2b(h);
    }

    if (t < T_DIM - 1) {
      __builtin_amdgcn_fence(__ATOMIC_RELEASE, "agent");  // flush h to L3
      if (lane == 0) atomicAdd(&bar[t], 1);
    }
  }

  // tail: [h_final | c_final]
  const size_t tail = (size_t)T_DIM * B_DIM * H_DIM;
#pragma unroll
  for (int rr = 0; rr < 4; ++rr) {
    const int b = rb + rr;
    out[tail + (size_t)b * 1024 + j] = hv[rr];
    out[tail + (size_t)B_DIM * H_DIM + (size_t)b * 1024 + j] = creg[rr];
  }
}

// ===========================================================================
extern "C" void kernel_launch(void* const* d_in, const int* in_sizes, int n_in,
                              void* d_out, int out_size, void* d_ws, size_t ws_size,
                              hipStream_t stream) {
  const float* x  = (const float*)d_in[0];
  const float* Wx = (const float*)d_in[1];
  const float* Wh = (const float*)d_in[2];
  const float* bh = (const float*)d_in[3];
  float* out = (float*)d_out;

  const size_t xg_bytes = (size_t)T_DIM * B_DIM * G_DIM * 2;   // 256 MiB
  const size_t wh_bytes = (size_t)G_DIM * H_DIM * 2;           // 8 MiB
  const size_t hb_bytes = (size_t)B_DIM * H_DIM * 2;           // 128 KiB
  char* ws = (char*)d_ws;

  ushort_t* xg  = (ushort_t*)ws;
  ushort_t* Whb = (ushort_t*)(ws + xg_bytes);
  ushort_t* hb0 = (ushort_t*)(ws + xg_bytes + wh_bytes);
  ushort_t* hb1 = (ushort_t*)(ws + xg_bytes + wh_bytes + hb_bytes);
  int*      bar = (int*)(ws + xg_bytes + wh_bytes + 2 * hb_bytes);

  reset_bar_kernel<<<2, 256, 0, stream>>>(bar);
  convert_bf16_kernel<<<(G_DIM * H_DIM / 8 + 255) / 256, 256, 0, stream>>>(
      Wh, Whb, G_DIM * H_DIM / 8);
  xg_gemm_mfma<<<dim3(T_DIM * B_DIM / 128, G_DIM / 128), 256, 0, stream>>>(
      x, Wx, bh, xg);
  lstm_persistent<<<NBLK, 64, 131072, stream>>>(xg, Whb, hb0, hb1, bar, out);
}

// Round 5
// 8574.458 us; speedup vs baseline: 1.2847x; 1.2847x over previous
//
#include <hip/hip_runtime.h>
#include <cstddef>
#include <cstdint>

// LSTM T=512 B=64 D=1024 H=1024.
//   Phase 1: xg = x @ Wx^T + bh -> bf16 (MFMA 128x128 tile GEMM, reg-staged f32->bf16)
//   Phase 2: ONE persistent kernel, 256 blocks x 1 wave (1 block/CU), 512 steps.
//            h exchanged through the coherence point (sc0sc1 write-through stores +
//            L2-bypassing loads via relaxed AGENT atomics) -> NO per-step L2
//            writeback/invalidate fences. Barrier = relaxed atomics on 8 stripes,
//            each stripe padded to its own 64B line (L3-bank parallel arrives).
//            Wh slice (128 KiB) in LDS per block; c in VGPRs; h global ping-pong.
// d_out = [outputs(T,B,H) | h(B,H) | c(B,H)] f32.

#define T_DIM 512
#define B_DIM 64
#define H_DIM 1024
#define G_DIM 4096
#define NBLK 256
#define BAR_STRIDE 16  // ints; one 64B line per stripe

typedef short short8 __attribute__((ext_vector_type(8)));
typedef float f32x4 __attribute__((ext_vector_type(4)));
typedef unsigned short ushort_t;

__device__ __forceinline__ ushort_t f2b(float f) {   // f32 -> bf16 RNE
  union { float f; unsigned u; } v; v.f = f;
  unsigned r = v.u + 0x7fffu + ((v.u >> 16) & 1u);
  return (ushort_t)(r >> 16);
}
__device__ __forceinline__ float b2f(ushort_t u) {
  union { unsigned u; float f; } v; v.u = ((unsigned)u) << 16;
  return v.f;
}
__device__ __forceinline__ float sigmoidf_(float x) { return 1.0f / (1.0f + __expf(-x)); }

// ---------------------------------------------------------------------------
__global__ __launch_bounds__(256) void reset_bar_kernel(int* __restrict__ bar) {
  int i = blockIdx.x * 256 + threadIdx.x;
  if (i < T_DIM * 8 * BAR_STRIDE) bar[i] = 0;
}

// convert f32 -> bf16 (Wh), 8 elems/thread
__global__ __launch_bounds__(256) void convert_bf16_kernel(
    const float* __restrict__ src, ushort_t* __restrict__ dst, int n8) {
  int i = blockIdx.x * 256 + threadIdx.x;
  if (i >= n8) return;
  float4 v0 = *(const float4*)&src[(size_t)i * 8];
  float4 v1 = *(const float4*)&src[(size_t)i * 8 + 4];
  ushort_t p[8] = {f2b(v0.x), f2b(v0.y), f2b(v0.z), f2b(v0.w),
                   f2b(v1.x), f2b(v1.y), f2b(v1.z), f2b(v1.w)};
  *(short8*)&dst[(size_t)i * 8] = *(const short8*)p;
}

// ---------------------------------------------------------------------------
// MFMA GEMM (unchanged): C[m][n] = bf16(sum_k x[m][k]*Wx[n][k] + bh[n])
__global__ __launch_bounds__(256) void xg_gemm_mfma(
    const float* __restrict__ A, const float* __restrict__ Bw,
    const float* __restrict__ bh, ushort_t* __restrict__ C) {
  __shared__ ushort_t As[128 * 64];
  __shared__ ushort_t Bs[128 * 64];
  const int tid = threadIdx.x;
  const int lane = tid & 63;
  const int w = tid >> 6;
  const int wm = w >> 1, wn = w & 1;
  const size_t m0 = (size_t)blockIdx.x * 128;
  const int n0 = blockIdx.y * 128;
  const int r = tid >> 1;
  const int kb = (tid & 1) * 32;

  f32x4 acc[4][4];
#pragma unroll
  for (int i = 0; i < 4; ++i)
#pragma unroll
    for (int j = 0; j < 4; ++j) acc[i][j] = 0.0f;

  const int lr = lane & 15;
  const int lk = (lane >> 4) * 8;

  for (int k0 = 0; k0 < 1024; k0 += 64) {
    __syncthreads();
#pragma unroll
    for (int i = 0; i < 4; ++i) {
      const int kk = kb + i * 8;
      float4 a0 = *(const float4*)&A[(m0 + r) * 1024 + k0 + kk];
      float4 a1 = *(const float4*)&A[(m0 + r) * 1024 + k0 + kk + 4];
      ushort_t pa[8] = {f2b(a0.x), f2b(a0.y), f2b(a0.z), f2b(a0.w),
                        f2b(a1.x), f2b(a1.y), f2b(a1.z), f2b(a1.w)};
      float4 b0 = *(const float4*)&Bw[(size_t)(n0 + r) * 1024 + k0 + kk];
      float4 b1 = *(const float4*)&Bw[(size_t)(n0 + r) * 1024 + k0 + kk + 4];
      ushort_t pb[8] = {f2b(b0.x), f2b(b0.y), f2b(b0.z), f2b(b0.w),
                        f2b(b1.x), f2b(b1.y), f2b(b1.z), f2b(b1.w)};
      const int byte = (r * 128 + kk * 2) ^ ((r & 7) << 4);
      *(short8*)((char*)As + byte) = *(const short8*)pa;
      *(short8*)((char*)Bs + byte) = *(const short8*)pb;
    }
    __syncthreads();
#pragma unroll
    for (int kk = 0; kk < 64; kk += 32) {
      short8 af[4], bf[4];
#pragma unroll
      for (int mf = 0; mf < 4; ++mf) {
        const int row = wm * 64 + mf * 16 + lr;
        const int byte = (row * 128 + (kk + lk) * 2) ^ ((row & 7) << 4);
        af[mf] = *(const short8*)((const char*)As + byte);
      }
#pragma unroll
      for (int nf = 0; nf < 4; ++nf) {
        const int row = wn * 64 + nf * 16 + lr;
        const int byte = (row * 128 + (kk + lk) * 2) ^ ((row & 7) << 4);
        bf[nf] = *(const short8*)((const char*)Bs + byte);
      }
#pragma unroll
      for (int mf = 0; mf < 4; ++mf)
#pragma unroll
        for (int nf = 0; nf < 4; ++nf)
          acc[mf][nf] = __builtin_amdgcn_mfma_f32_16x16x32_bf16(
              af[mf], bf[nf], acc[mf][nf], 0, 0, 0);
    }
  }
#pragma unroll
  for (int nf = 0; nf < 4; ++nf) {
    const int col = n0 + wn * 64 + nf * 16 + lr;
    const float bias = bh[col];
#pragma unroll
    for (int mf = 0; mf < 4; ++mf) {
      const size_t row0 = m0 + wm * 64 + mf * 16 + (lane >> 4) * 4;
#pragma unroll
      for (int rr = 0; rr < 4; ++rr)
        C[(row0 + rr) * 4096 + col] = f2b(acc[mf][nf][rr] + bias);
    }
  }
}

// ---------------------------------------------------------------------------
// Persistent recurrence, fence-free h exchange.
// Block b: j0=(b>>2)*16, w=b&3 (batch quarter). Wave: 16 j x 4 gates x 16 batches.
__global__ __launch_bounds__(64) void lstm_persistent(
    const ushort_t* __restrict__ xg,   // [T*64][4096] bf16 (bias folded)
    const ushort_t* __restrict__ Whb,  // [4096][1024] bf16
    ushort_t* __restrict__ hb0,        // [64][1024] bf16 ping
    ushort_t* __restrict__ hb1,        // [64][1024] bf16 pong
    int* __restrict__ bar,             // [T*8*BAR_STRIDE] arrive counters (zeroed)
    float* __restrict__ out) {         // [T][64][1024] f32 + tail
  extern __shared__ ushort_t Wlds[];   // 64 rows x 1024 bf16 = 128 KiB
  const int lane = threadIdx.x;
  const int bid = (int)blockIdx.x;
  const int j0 = (bid >> 2) * 16;
  const int w  = bid & 3;
  const int lr = lane & 15;
  const int lq = lane >> 4;            // 0..3
  const int j  = j0 + lr;
  const int rb = w * 16 + lq * 4;      // epilogue batch base
  const int ko = lq * 8;               // A-frag k offset (elements)

  // one-time: stage this block's Wh slice into LDS (swizzled)
  for (int e = lane; e < 8192; e += 64) {
    const int r  = e >> 7;             // LDS row 0..63 (= gate*16 + jj)
    const int ch = e & 127;            // 16B chunk within row
    const int gr = (r >> 4) * 1024 + j0 + (r & 15);
    short8 v = *(const short8*)(Whb + (size_t)gr * 1024 + ch * 8);
    const int byte = (r * 2048 + ch * 16) ^ ((r & 7) << 4);
    *(short8*)((char*)Wlds + byte) = v;
  }

  float creg[4] = {0.f, 0.f, 0.f, 0.f};
  float hv[4];

  for (int t = 0; t < T_DIM; ++t) {
    // prefetch xg[t] (independent of h) before the spin
    float xgv[4][4];
#pragma unroll
    for (int rr = 0; rr < 4; ++rr) {
      const size_t base = ((size_t)t * 64 + rb + rr) * 4096 + j;
#pragma unroll
      for (int g = 0; g < 4; ++g) xgv[g][rr] = b2f(xg[base + (size_t)g * 1024]);
    }

    f32x4 acc[4];
#pragma unroll
    for (int g = 0; g < 4; ++g) acc[g] = 0.f;

    if (t > 0) {
      // spin on striped counters (relaxed agent loads; lanes cover 8 stripes)
      const int t8 = (t - 1) << 3;
      for (;;) {
        int v = __hip_atomic_load(&bar[(t8 + (lane & 7)) * BAR_STRIDE],
                                  __ATOMIC_RELAXED, __HIP_MEMORY_SCOPE_AGENT);
        if (__all(v >= NBLK / 8)) break;
        __builtin_amdgcn_s_sleep(2);
      }
      // h loads: L2-bypassing (sc0 sc1) 8B relaxed agent atomics
      const ushort_t* hprev = (t & 1) ? hb0 : hb1;
      const unsigned long long* hrow = (const unsigned long long*)(
          hprev + (size_t)(w * 16 + lr) * 1024 + ko);
      short8 af[32];
#pragma unroll 8
      for (int ks = 0; ks < 32; ++ks) {
        union { unsigned long long u[2]; short8 s; } av;
        av.u[0] = __hip_atomic_load(hrow + ks * 8, __ATOMIC_RELAXED,
                                    __HIP_MEMORY_SCOPE_AGENT);
        av.u[1] = __hip_atomic_load(hrow + ks * 8 + 1, __ATOMIC_RELAXED,
                                    __HIP_MEMORY_SCOPE_AGENT);
        af[ks] = av.s;
      }
#pragma unroll 8
      for (int ks = 0; ks < 32; ++ks) {
#pragma unroll
        for (int g = 0; g < 4; ++g) {
          const int row = g * 16 + lr;
          const int byte = (row * 2048 + ks * 64 + lq * 16) ^ ((row & 7) << 4);
          short8 bfrag = *(const short8*)((const char*)Wlds + byte);
          acc[g] = __builtin_amdgcn_mfma_f32_16x16x32_bf16(af[ks], bfrag,
                                                           acc[g], 0, 0, 0);
        }
      }
    }

    ushort_t* hcur = (t & 1) ? hb1 : hb0;
#pragma unroll
    for (int rr = 0; rr < 4; ++rr) {
      const int b = rb + rr;
      const float ig = sigmoidf_(acc[0][rr] + xgv[0][rr]);
      const float fg = sigmoidf_(acc[1][rr] + xgv[1][rr]);
      const float gg = tanhf(acc[2][rr] + xgv[2][rr]);
      const float og = sigmoidf_(acc[3][rr] + xgv[3][rr]);
      const float cn = fmaf(fg, creg[rr], ig * gg);
      creg[rr] = cn;
      const float h = og * tanhf(cn);
      hv[rr] = h;
      out[((size_t)t * 64 + b) * 1024 + j] = h;
      // write-through (sc0 sc1) store -> visible at coherence point, no fence
      __hip_atomic_store(&hcur[(size_t)b * 1024 + j], f2b(h), __ATOMIC_RELAXED,
                         __HIP_MEMORY_SCOPE_AGENT);
    }

    if (t < T_DIM - 1) {
      // drain stores, then arrive (own 64B line per stripe, relaxed)
      asm volatile("s_waitcnt vmcnt(0)" ::: "memory");
      if (lane == 0)
        __hip_atomic_fetch_add(&bar[((t << 3) + (bid & 7)) * BAR_STRIDE], 1,
                               __ATOMIC_RELAXED, __HIP_MEMORY_SCOPE_AGENT);
    }
  }

  // tail: [h_final | c_final]
  const size_t tail = (size_t)T_DIM * B_DIM * H_DIM;
#pragma unroll
  for (int rr = 0; rr < 4; ++rr) {
    const int b = rb + rr;
    out[tail + (size_t)b * 1024 + j] = hv[rr];
    out[tail + (size_t)B_DIM * H_DIM + (size_t)b * 1024 + j] = creg[rr];
  }
}

// ===========================================================================
extern "C" void kernel_launch(void* const* d_in, const int* in_sizes, int n_in,
                              void* d_out, int out_size, void* d_ws, size_t ws_size,
                              hipStream_t stream) {
  const float* x  = (const float*)d_in[0];
  const float* Wx = (const float*)d_in[1];
  const float* Wh = (const float*)d_in[2];
  const float* bh = (const float*)d_in[3];
  float* out = (float*)d_out;

  const size_t xg_bytes = (size_t)T_DIM * B_DIM * G_DIM * 2;   // 256 MiB
  const size_t wh_bytes = (size_t)G_DIM * H_DIM * 2;           // 8 MiB
  const size_t hb_bytes = (size_t)B_DIM * H_DIM * 2;           // 128 KiB
  char* ws = (char*)d_ws;

  ushort_t* xg  = (ushort_t*)ws;
  ushort_t* Whb = (ushort_t*)(ws + xg_bytes);
  ushort_t* hb0 = (ushort_t*)(ws + xg_bytes + wh_bytes);
  ushort_t* hb1 = (ushort_t*)(ws + xg_bytes + wh_bytes + hb_bytes);
  int*      bar = (int*)(ws + xg_bytes + wh_bytes + 2 * hb_bytes);

  reset_bar_kernel<<<(T_DIM * 8 * BAR_STRIDE) / 256, 256, 0, stream>>>(bar);
  convert_bf16_kernel<<<(G_DIM * H_DIM / 8 + 255) / 256, 256, 0, stream>>>(
      Wh, Whb, G_DIM * H_DIM / 8);
  xg_gemm_mfma<<<dim3(T_DIM * B_DIM / 128, G_DIM / 128), 256, 0, stream>>>(
      x, Wx, bh, xg);
  lstm_persistent<<<NBLK, 64, 131072, stream>>>(xg, Whb, hb0, hb1, bar, out);
}

// Round 6
// 8415.244 us; speedup vs baseline: 1.3090x; 1.0189x over previous
//
#include <hip/hip_runtime.h>
#include <cstddef>
#include <cstdint>

// LSTM T=512 B=64 D=1024 H=1024.
//   Phase 1: xg = x @ Wx^T + bh -> bf16 (MFMA 128x128 tile GEMM, reg-staged f32->bf16)
//   Phase 2: ONE persistent kernel, 256 blocks x 1 wave (1 block/CU), 512 steps.
//            h exchanged via sc0sc1 write-through stores + L2-bypassing agent loads
//            (no L2 wb/inv fences). Barrier: FOUR independent batch-quarter
//            barriers (64 parties each); lane-0-only poll of one padded counter
//            per (t, quarter); out[] stores moved off the critical path.
//            Wh slice (128 KiB) in LDS per block; c in VGPRs; h global ping-pong.
// d_out = [outputs(T,B,H) | h(B,H) | c(B,H)] f32.

#define T_DIM 512
#define B_DIM 64
#define H_DIM 1024
#define G_DIM 4096
#define NBLK 256
#define QBLK 64        // blocks per batch-quarter barrier
#define BAR_STRIDE 16  // ints; one 64B line per counter

typedef short short8 __attribute__((ext_vector_type(8)));
typedef float f32x4 __attribute__((ext_vector_type(4)));
typedef unsigned short ushort_t;

__device__ __forceinline__ ushort_t f2b(float f) {   // f32 -> bf16 RNE
  union { float f; unsigned u; } v; v.f = f;
  unsigned r = v.u + 0x7fffu + ((v.u >> 16) & 1u);
  return (ushort_t)(r >> 16);
}
__device__ __forceinline__ float b2f(ushort_t u) {
  union { unsigned u; float f; } v; v.u = ((unsigned)u) << 16;
  return v.f;
}
__device__ __forceinline__ float sigmoidf_(float x) { return 1.0f / (1.0f + __expf(-x)); }

// ---------------------------------------------------------------------------
__global__ __launch_bounds__(256) void reset_bar_kernel(int* __restrict__ bar) {
  int i = blockIdx.x * 256 + threadIdx.x;
  if (i < T_DIM * 4 * BAR_STRIDE) bar[i] = 0;
}

// convert f32 -> bf16 (Wh), 8 elems/thread
__global__ __launch_bounds__(256) void convert_bf16_kernel(
    const float* __restrict__ src, ushort_t* __restrict__ dst, int n8) {
  int i = blockIdx.x * 256 + threadIdx.x;
  if (i >= n8) return;
  float4 v0 = *(const float4*)&src[(size_t)i * 8];
  float4 v1 = *(const float4*)&src[(size_t)i * 8 + 4];
  ushort_t p[8] = {f2b(v0.x), f2b(v0.y), f2b(v0.z), f2b(v0.w),
                   f2b(v1.x), f2b(v1.y), f2b(v1.z), f2b(v1.w)};
  *(short8*)&dst[(size_t)i * 8] = *(const short8*)p;
}

// ---------------------------------------------------------------------------
// MFMA GEMM (unchanged): C[m][n] = bf16(sum_k x[m][k]*Wx[n][k] + bh[n])
__global__ __launch_bounds__(256) void xg_gemm_mfma(
    const float* __restrict__ A, const float* __restrict__ Bw,
    const float* __restrict__ bh, ushort_t* __restrict__ C) {
  __shared__ ushort_t As[128 * 64];
  __shared__ ushort_t Bs[128 * 64];
  const int tid = threadIdx.x;
  const int lane = tid & 63;
  const int w = tid >> 6;
  const int wm = w >> 1, wn = w & 1;
  const size_t m0 = (size_t)blockIdx.x * 128;
  const int n0 = blockIdx.y * 128;
  const int r = tid >> 1;
  const int kb = (tid & 1) * 32;

  f32x4 acc[4][4];
#pragma unroll
  for (int i = 0; i < 4; ++i)
#pragma unroll
    for (int j = 0; j < 4; ++j) acc[i][j] = 0.0f;

  const int lr = lane & 15;
  const int lk = (lane >> 4) * 8;

  for (int k0 = 0; k0 < 1024; k0 += 64) {
    __syncthreads();
#pragma unroll
    for (int i = 0; i < 4; ++i) {
      const int kk = kb + i * 8;
      float4 a0 = *(const float4*)&A[(m0 + r) * 1024 + k0 + kk];
      float4 a1 = *(const float4*)&A[(m0 + r) * 1024 + k0 + kk + 4];
      ushort_t pa[8] = {f2b(a0.x), f2b(a0.y), f2b(a0.z), f2b(a0.w),
                        f2b(a1.x), f2b(a1.y), f2b(a1.z), f2b(a1.w)};
      float4 b0 = *(const float4*)&Bw[(size_t)(n0 + r) * 1024 + k0 + kk];
      float4 b1 = *(const float4*)&Bw[(size_t)(n0 + r) * 1024 + k0 + kk + 4];
      ushort_t pb[8] = {f2b(b0.x), f2b(b0.y), f2b(b0.z), f2b(b0.w),
                        f2b(b1.x), f2b(b1.y), f2b(b1.z), f2b(b1.w)};
      const int byte = (r * 128 + kk * 2) ^ ((r & 7) << 4);
      *(short8*)((char*)As + byte) = *(const short8*)pa;
      *(short8*)((char*)Bs + byte) = *(const short8*)pb;
    }
    __syncthreads();
#pragma unroll
    for (int kk = 0; kk < 64; kk += 32) {
      short8 af[4], bf[4];
#pragma unroll
      for (int mf = 0; mf < 4; ++mf) {
        const int row = wm * 64 + mf * 16 + lr;
        const int byte = (row * 128 + (kk + lk) * 2) ^ ((row & 7) << 4);
        af[mf] = *(const short8*)((const char*)As + byte);
      }
#pragma unroll
      for (int nf = 0; nf < 4; ++nf) {
        const int row = wn * 64 + nf * 16 + lr;
        const int byte = (row * 128 + (kk + lk) * 2) ^ ((row & 7) << 4);
        bf[nf] = *(const short8*)((const char*)Bs + byte);
      }
#pragma unroll
      for (int mf = 0; mf < 4; ++mf)
#pragma unroll
        for (int nf = 0; nf < 4; ++nf)
          acc[mf][nf] = __builtin_amdgcn_mfma_f32_16x16x32_bf16(
              af[mf], bf[nf], acc[mf][nf], 0, 0, 0);
    }
  }
#pragma unroll
  for (int nf = 0; nf < 4; ++nf) {
    const int col = n0 + wn * 64 + nf * 16 + lr;
    const float bias = bh[col];
#pragma unroll
    for (int mf = 0; mf < 4; ++mf) {
      const size_t row0 = m0 + wm * 64 + mf * 16 + (lane >> 4) * 4;
#pragma unroll
      for (int rr = 0; rr < 4; ++rr)
        C[(row0 + rr) * 4096 + col] = f2b(acc[mf][nf][rr] + bias);
    }
  }
}

// ---------------------------------------------------------------------------
// Persistent recurrence. Block b: j0=(b>>2)*16, w=b&3 (batch quarter).
// Wave: 16 j x 4 gates x 16 batches. Per-quarter barrier: block (j0,w) only
// reads h rows [16w,16w+16), written exclusively by same-w blocks.
__global__ __launch_bounds__(64) void lstm_persistent(
    const ushort_t* __restrict__ xg,   // [T*64][4096] bf16 (bias folded)
    const ushort_t* __restrict__ Whb,  // [4096][1024] bf16
    ushort_t* __restrict__ hb0,        // [64][1024] bf16 ping
    ushort_t* __restrict__ hb1,        // [64][1024] bf16 pong
    int* __restrict__ bar,             // [T*4*BAR_STRIDE] arrive counters (zeroed)
    float* __restrict__ out) {         // [T][64][1024] f32 + tail
  extern __shared__ ushort_t Wlds[];   // 64 rows x 1024 bf16 = 128 KiB
  const int lane = threadIdx.x;
  const int bid = (int)blockIdx.x;
  const int j0 = (bid >> 2) * 16;
  const int w  = bid & 3;
  const int lr = lane & 15;
  const int lq = lane >> 4;            // 0..3
  const int j  = j0 + lr;
  const int rb = w * 16 + lq * 4;      // epilogue batch base
  const int ko = lq * 8;               // A-frag k offset (elements)

  // one-time: stage this block's Wh slice into LDS (swizzled)
  for (int e = lane; e < 8192; e += 64) {
    const int r  = e >> 7;             // LDS row 0..63 (= gate*16 + jj)
    const int ch = e & 127;            // 16B chunk within row
    const int gr = (r >> 4) * 1024 + j0 + (r & 15);
    short8 v = *(const short8*)(Whb + (size_t)gr * 1024 + ch * 8);
    const int byte = (r * 2048 + ch * 16) ^ ((r & 7) << 4);
    *(short8*)((char*)Wlds + byte) = v;
  }

  float creg[4] = {0.f, 0.f, 0.f, 0.f};
  float hv[4];

  for (int t = 0; t < T_DIM; ++t) {
    // prefetch xg[t] (independent of h) before the spin
    float xgv[4][4];
#pragma unroll
    for (int rr = 0; rr < 4; ++rr) {
      const size_t base = ((size_t)t * 64 + rb + rr) * 4096 + j;
#pragma unroll
      for (int g = 0; g < 4; ++g) xgv[g][rr] = b2f(xg[base + (size_t)g * 1024]);
    }

    f32x4 acc[4];
#pragma unroll
    for (int g = 0; g < 4; ++g) acc[g] = 0.f;

    if (t > 0) {
      // lane-0-only poll of this quarter's arrive counter (1 L3 line)
      if (lane == 0) {
        const int* ctr = &bar[((t - 1) * 4 + w) * BAR_STRIDE];
        while (__hip_atomic_load(ctr, __ATOMIC_RELAXED,
                                 __HIP_MEMORY_SCOPE_AGENT) < QBLK)
          __builtin_amdgcn_s_sleep(1);
      }
      // h loads: L2-bypassing 8B relaxed agent atomics
      const ushort_t* hprev = (t & 1) ? hb0 : hb1;
      const unsigned long long* hrow = (const unsigned long long*)(
          hprev + (size_t)(w * 16 + lr) * 1024 + ko);
      short8 af[32];
#pragma unroll 8
      for (int ks = 0; ks < 32; ++ks) {
        union { unsigned long long u[2]; short8 s; } av;
        av.u[0] = __hip_atomic_load(hrow + ks * 8, __ATOMIC_RELAXED,
                                    __HIP_MEMORY_SCOPE_AGENT);
        av.u[1] = __hip_atomic_load(hrow + ks * 8 + 1, __ATOMIC_RELAXED,
                                    __HIP_MEMORY_SCOPE_AGENT);
        af[ks] = av.s;
      }
#pragma unroll 8
      for (int ks = 0; ks < 32; ++ks) {
#pragma unroll
        for (int g = 0; g < 4; ++g) {
          const int row = g * 16 + lr;
          const int byte = (row * 2048 + ks * 64 + lq * 16) ^ ((row & 7) << 4);
          short8 bfrag = *(const short8*)((const char*)Wlds + byte);
          acc[g] = __builtin_amdgcn_mfma_f32_16x16x32_bf16(af[ks], bfrag,
                                                           acc[g], 0, 0, 0);
        }
      }
    }

    // cell update; store h (write-through) FIRST -- it's the only inter-block dep
    ushort_t* hcur = (t & 1) ? hb1 : hb0;
#pragma unroll
    for (int rr = 0; rr < 4; ++rr) {
      const int b = rb + rr;
      const float ig = sigmoidf_(acc[0][rr] + xgv[0][rr]);
      const float fg = sigmoidf_(acc[1][rr] + xgv[1][rr]);
      const float gg = tanhf(acc[2][rr] + xgv[2][rr]);
      const float og = sigmoidf_(acc[3][rr] + xgv[3][rr]);
      const float cn = fmaf(fg, creg[rr], ig * gg);
      creg[rr] = cn;
      const float h = og * tanhf(cn);
      hv[rr] = h;
      __hip_atomic_store(&hcur[(size_t)b * 1024 + j], f2b(h), __ATOMIC_RELAXED,
                         __HIP_MEMORY_SCOPE_AGENT);
    }

    if (t < T_DIM - 1) {
      // drain h stores, then arrive at this quarter's counter
      asm volatile("s_waitcnt vmcnt(0)" ::: "memory");
      if (lane == 0)
        __hip_atomic_fetch_add(&bar[(t * 4 + w) * BAR_STRIDE], 1,
                               __ATOMIC_RELAXED, __HIP_MEMORY_SCOPE_AGENT);
    }

    // out[] stores AFTER arrive -- off the inter-block critical path
#pragma unroll
    for (int rr = 0; rr < 4; ++rr)
      out[((size_t)t * 64 + rb + rr) * 1024 + j] = hv[rr];
  }

  // tail: [h_final | c_final]
  const size_t tail = (size_t)T_DIM * B_DIM * H_DIM;
#pragma unroll
  for (int rr = 0; rr < 4; ++rr) {
    const int b = rb + rr;
    out[tail + (size_t)b * 1024 + j] = hv[rr];
    out[tail + (size_t)B_DIM * H_DIM + (size_t)b * 1024 + j] = creg[rr];
  }
}

// ===========================================================================
extern "C" void kernel_launch(void* const* d_in, const int* in_sizes, int n_in,
                              void* d_out, int out_size, void* d_ws, size_t ws_size,
                              hipStream_t stream) {
  const float* x  = (const float*)d_in[0];
  const float* Wx = (const float*)d_in[1];
  const float* Wh = (const float*)d_in[2];
  const float* bh = (const float*)d_in[3];
  float* out = (float*)d_out;

  const size_t xg_bytes = (size_t)T_DIM * B_DIM * G_DIM * 2;   // 256 MiB
  const size_t wh_bytes = (size_t)G_DIM * H_DIM * 2;           // 8 MiB
  const size_t hb_bytes = (size_t)B_DIM * H_DIM * 2;           // 128 KiB
  char* ws = (char*)d_ws;

  ushort_t* xg  = (ushort_t*)ws;
  ushort_t* Whb = (ushort_t*)(ws + xg_bytes);
  ushort_t* hb0 = (ushort_t*)(ws + xg_bytes + wh_bytes);
  ushort_t* hb1 = (ushort_t*)(ws + xg_bytes + wh_bytes + hb_bytes);
  int*      bar = (int*)(ws + xg_bytes + wh_bytes + 2 * hb_bytes);

  reset_bar_kernel<<<(T_DIM * 4 * BAR_STRIDE) / 256, 256, 0, stream>>>(bar);
  convert_bf16_kernel<<<(G_DIM * H_DIM / 8 + 255) / 256, 256, 0, stream>>>(
      Wh, Whb, G_DIM * H_DIM / 8);
  xg_gemm_mfma<<<dim3(T_DIM * B_DIM / 128, G_DIM / 128), 256, 0, stream>>>(
      x, Wx, bh, xg);
  lstm_persistent<<<NBLK, 64, 131072, stream>>>(xg, Whb, hb0, hb1, bar, out);
}

// Round 8
// 3609.981 us; speedup vs baseline: 3.0513x; 2.3311x over previous
//
#include <hip/hip_runtime.h>
#include <cstddef>
#include <cstdint>

// LSTM T=512 B=64 D=1024 H=1024.
//   Phase 1: xg = x @ Wx^T + bh -> bf16 (MFMA 128x128 tile GEMM)
//   Phase 2: ONE persistent kernel, 256 blocks x 4 waves (k-split), 512 steps.
//            Wave v: partial gates over ks in [8v,8v+8); LDS reduce; epilogue
//            distributed 1 (b,j) per lane. h exchanged via sc0sc1 write-through
//            stores + L2-bypassing agent loads. Per-quarter barrier (64 parties),
//            lane0-of-wave0 sleepless spin. Wh slice 128 KiB LDS; c in VGPRs.
// R8 fix vs R7: h-fragment k-stride was i*4 u64 (32B) -- must be i*8 u64 (64B =
// 32 bf16 per k-step). A-frags read wrong k slices -> absmax 0.34. One-line fix.
// d_out = [outputs(T,B,H) | h(B,H) | c(B,H)] f32.

#define T_DIM 512
#define B_DIM 64
#define H_DIM 1024
#define G_DIM 4096
#define NBLK 256
#define QBLK 64        // blocks per batch-quarter barrier
#define BAR_STRIDE 16  // ints; one 64B line per counter

typedef short short8 __attribute__((ext_vector_type(8)));
typedef float f32x4 __attribute__((ext_vector_type(4)));
typedef unsigned short ushort_t;

__device__ __forceinline__ ushort_t f2b(float f) {   // f32 -> bf16 RNE
  union { float f; unsigned u; } v; v.f = f;
  unsigned r = v.u + 0x7fffu + ((v.u >> 16) & 1u);
  return (ushort_t)(r >> 16);
}
__device__ __forceinline__ float b2f(ushort_t u) {
  union { unsigned u; float f; } v; v.u = ((unsigned)u) << 16;
  return v.f;
}
__device__ __forceinline__ float sigmoidf_(float x) { return 1.0f / (1.0f + __expf(-x)); }

// ---------------------------------------------------------------------------
__global__ __launch_bounds__(256) void reset_bar_kernel(int* __restrict__ bar) {
  int i = blockIdx.x * 256 + threadIdx.x;
  if (i < T_DIM * 4 * BAR_STRIDE) bar[i] = 0;
}

// convert f32 -> bf16 (Wh), 8 elems/thread
__global__ __launch_bounds__(256) void convert_bf16_kernel(
    const float* __restrict__ src, ushort_t* __restrict__ dst, int n8) {
  int i = blockIdx.x * 256 + threadIdx.x;
  if (i >= n8) return;
  float4 v0 = *(const float4*)&src[(size_t)i * 8];
  float4 v1 = *(const float4*)&src[(size_t)i * 8 + 4];
  ushort_t p[8] = {f2b(v0.x), f2b(v0.y), f2b(v0.z), f2b(v0.w),
                   f2b(v1.x), f2b(v1.y), f2b(v1.z), f2b(v1.w)};
  *(short8*)&dst[(size_t)i * 8] = *(const short8*)p;
}

// ---------------------------------------------------------------------------
// MFMA GEMM (unchanged): C[m][n] = bf16(sum_k x[m][k]*Wx[n][k] + bh[n])
__global__ __launch_bounds__(256) void xg_gemm_mfma(
    const float* __restrict__ A, const float* __restrict__ Bw,
    const float* __restrict__ bh, ushort_t* __restrict__ C) {
  __shared__ ushort_t As[128 * 64];
  __shared__ ushort_t Bs[128 * 64];
  const int tid = threadIdx.x;
  const int lane = tid & 63;
  const int w = tid >> 6;
  const int wm = w >> 1, wn = w & 1;
  const size_t m0 = (size_t)blockIdx.x * 128;
  const int n0 = blockIdx.y * 128;
  const int r = tid >> 1;
  const int kb = (tid & 1) * 32;

  f32x4 acc[4][4];
#pragma unroll
  for (int i = 0; i < 4; ++i)
#pragma unroll
    for (int j = 0; j < 4; ++j) acc[i][j] = 0.0f;

  const int lr = lane & 15;
  const int lk = (lane >> 4) * 8;

  for (int k0 = 0; k0 < 1024; k0 += 64) {
    __syncthreads();
#pragma unroll
    for (int i = 0; i < 4; ++i) {
      const int kk = kb + i * 8;
      float4 a0 = *(const float4*)&A[(m0 + r) * 1024 + k0 + kk];
      float4 a1 = *(const float4*)&A[(m0 + r) * 1024 + k0 + kk + 4];
      ushort_t pa[8] = {f2b(a0.x), f2b(a0.y), f2b(a0.z), f2b(a0.w),
                        f2b(a1.x), f2b(a1.y), f2b(a1.z), f2b(a1.w)};
      float4 b0 = *(const float4*)&Bw[(size_t)(n0 + r) * 1024 + k0 + kk];
      float4 b1 = *(const float4*)&Bw[(size_t)(n0 + r) * 1024 + k0 + kk + 4];
      ushort_t pb[8] = {f2b(b0.x), f2b(b0.y), f2b(b0.z), f2b(b0.w),
                        f2b(b1.x), f2b(b1.y), f2b(b1.z), f2b(b1.w)};
      const int byte = (r * 128 + kk * 2) ^ ((r & 7) << 4);
      *(short8*)((char*)As + byte) = *(const short8*)pa;
      *(short8*)((char*)Bs + byte) = *(const short8*)pb;
    }
    __syncthreads();
#pragma unroll
    for (int kk = 0; kk < 64; kk += 32) {
      short8 af[4], bf[4];
#pragma unroll
      for (int mf = 0; mf < 4; ++mf) {
        const int row = wm * 64 + mf * 16 + lr;
        const int byte = (row * 128 + (kk + lk) * 2) ^ ((row & 7) << 4);
        af[mf] = *(const short8*)((const char*)As + byte);
      }
#pragma unroll
      for (int nf = 0; nf < 4; ++nf) {
        const int row = wn * 64 + nf * 16 + lr;
        const int byte = (row * 128 + (kk + lk) * 2) ^ ((row & 7) << 4);
        bf[nf] = *(const short8*)((const char*)Bs + byte);
      }
#pragma unroll
      for (int mf = 0; mf < 4; ++mf)
#pragma unroll
        for (int nf = 0; nf < 4; ++nf)
          acc[mf][nf] = __builtin_amdgcn_mfma_f32_16x16x32_bf16(
              af[mf], bf[nf], acc[mf][nf], 0, 0, 0);
    }
  }
#pragma unroll
  for (int nf = 0; nf < 4; ++nf) {
    const int col = n0 + wn * 64 + nf * 16 + lr;
    const float bias = bh[col];
#pragma unroll
    for (int mf = 0; mf < 4; ++mf) {
      const size_t row0 = m0 + wm * 64 + mf * 16 + (lane >> 4) * 4;
#pragma unroll
      for (int rr = 0; rr < 4; ++rr)
        C[(row0 + rr) * 4096 + col] = f2b(acc[mf][nf][rr] + bias);
    }
  }
}

// ---------------------------------------------------------------------------
// Persistent recurrence, 4-wave k-split.
// Block b: j0=(b>>2)*16, w=b&3. Wave v handles ks in [8v, 8v+8).
// MFMA lane mapping (all waves): A-row = w*16+lr (batch), C: col=lr -> j,
//   row = lq*4+rr -> batch w*16+lq*4+rr.
// Epilogue: wave v, lane (lq,lr) owns (b = w*16+v*4+lq, j = j0+lr).
__global__ __launch_bounds__(256) void lstm_persistent(
    const ushort_t* __restrict__ xg,   // [T*64][4096] bf16 (bias folded)
    const ushort_t* __restrict__ Whb,  // [4096][1024] bf16
    ushort_t* __restrict__ hb0,        // [64][1024] bf16 ping
    ushort_t* __restrict__ hb1,        // [64][1024] bf16 pong
    int* __restrict__ bar,             // [T*4*BAR_STRIDE] arrive counters (zeroed)
    float* __restrict__ out) {         // [T][64][1024] f32 + tail
  extern __shared__ char smem[];
  ushort_t* Wlds = (ushort_t*)smem;            // 128 KiB, XOR-swizzled
  float* accs = (float*)(smem + 131072);       // 16 KiB reduce buffer
  const int tid = threadIdx.x;
  const int lane = tid & 63;
  const int v = tid >> 6;              // wave id = k-slice
  const int bid = (int)blockIdx.x;
  const int j0 = (bid >> 2) * 16;
  const int w  = bid & 3;
  const int lr = lane & 15;
  const int lq = lane >> 4;            // 0..3

  // epilogue-owned element
  const int bmine = w * 16 + v * 4 + lq;
  const int jmine = j0 + lr;

  // one-time: stage this block's Wh slice into LDS (swizzled), 256 threads
  for (int e = tid; e < 8192; e += 256) {
    const int r  = e >> 7;             // LDS row 0..63 (= gate*16 + jj)
    const int ch = e & 127;            // 16B chunk within row
    const int gr = (r >> 4) * 1024 + j0 + (r & 15);
    short8 val = *(const short8*)(Whb + (size_t)gr * 1024 + ch * 8);
    const int byte = (r * 2048 + ch * 16) ^ ((r & 7) << 4);
    *(short8*)((char*)Wlds + byte) = val;
  }
  __syncthreads();

  float creg = 0.f;
  float hv = 0.f;

  for (int t = 0; t < T_DIM; ++t) {
    // prefetch this lane's xg (independent of h) before the spin
    const size_t xbase = ((size_t)t * 64 + bmine) * 4096 + jmine;
    float xgv[4];
#pragma unroll
    for (int g = 0; g < 4; ++g) xgv[g] = b2f(xg[xbase + (size_t)g * 1024]);

    f32x4 acc[4];
#pragma unroll
    for (int g = 0; g < 4; ++g) acc[g] = 0.f;

    if (t > 0) {
      // sleepless spin: lane0 of wave0 only; natural backoff = L3 load latency
      if (tid == 0) {
        const int* ctr = &bar[((t - 1) * 4 + w) * BAR_STRIDE];
        while (__hip_atomic_load(ctr, __ATOMIC_RELAXED,
                                 __HIP_MEMORY_SCOPE_AGENT) < QBLK) {}
      }
      __syncthreads();  // sync1: release all waves

      // h loads: wave v covers ks in [8v, 8v+8); k-step = 32 bf16 = 64 B = 8 u64
      const ushort_t* hprev = (t & 1) ? hb0 : hb1;
      const unsigned long long* hrow = (const unsigned long long*)(
          hprev + (size_t)(w * 16 + lr) * 1024 + v * 256 + lq * 8);
      short8 af[8];
#pragma unroll
      for (int i = 0; i < 8; ++i) {
        union { unsigned long long u[2]; short8 s; } av;
        av.u[0] = __hip_atomic_load(hrow + i * 8, __ATOMIC_RELAXED,
                                    __HIP_MEMORY_SCOPE_AGENT);
        av.u[1] = __hip_atomic_load(hrow + i * 8 + 1, __ATOMIC_RELAXED,
                                    __HIP_MEMORY_SCOPE_AGENT);
        af[i] = av.s;
      }
#pragma unroll
      for (int i = 0; i < 8; ++i) {
        const int ksg = v * 8 + i;
#pragma unroll
        for (int g = 0; g < 4; ++g) {
          const int row = g * 16 + lr;
          const int byte = (row * 2048 + ksg * 64 + lq * 16) ^ ((row & 7) << 4);
          short8 bfrag = *(const short8*)((const char*)Wlds + byte);
          acc[g] = __builtin_amdgcn_mfma_f32_16x16x32_bf16(af[i], bfrag,
                                                           acc[g], 0, 0, 0);
        }
      }
    } else {
      __syncthreads();  // sync1 (uniform count)
    }

    // write partials to LDS: [(v*4+g)*64 + lane] * f32x4
#pragma unroll
    for (int g = 0; g < 4; ++g)
      *(f32x4*)&accs[((v * 4 + g) * 64 + lane) * 4] = acc[g];
    __syncthreads();  // sync2

    // epilogue: reduce 4 partials per gate for my (bmine, jmine)
    // partial for (b = w*16 + lq2*4 + rr, j = j0+lr2) is at
    //   accs[((v2*4+g)*64 + lq2*16 + lr2)*4 + rr]; here lq2 = v, rr = lq, lr2 = lr.
    float gv[4];
#pragma unroll
    for (int g = 0; g < 4; ++g) {
      float s = xgv[g];
#pragma unroll
      for (int v2 = 0; v2 < 4; ++v2)
        s += accs[((v2 * 4 + g) * 64 + v * 16 + lr) * 4 + lq];
      gv[g] = s;
    }
    const float ig = sigmoidf_(gv[0]);
    const float fg = sigmoidf_(gv[1]);
    const float gg = tanhf(gv[2]);
    const float og = sigmoidf_(gv[3]);
    const float cn = fmaf(fg, creg, ig * gg);
    creg = cn;
    hv = og * tanhf(cn);

    // h store (write-through, visible at L3), then block-wide drain
    ushort_t* hcur = (t & 1) ? hb1 : hb0;
    __hip_atomic_store(&hcur[(size_t)bmine * 1024 + jmine], f2b(hv),
                       __ATOMIC_RELAXED, __HIP_MEMORY_SCOPE_AGENT);
    asm volatile("s_waitcnt vmcnt(0)" ::: "memory");
    __syncthreads();  // sync3: all waves' h stores drained

    if (t < T_DIM - 1 && tid == 0)
      __hip_atomic_fetch_add(&bar[(t * 4 + w) * BAR_STRIDE], 1,
                             __ATOMIC_RELAXED, __HIP_MEMORY_SCOPE_AGENT);

    // out[] store after arrive -- off the inter-block critical path
    out[((size_t)t * 64 + bmine) * 1024 + jmine] = hv;
  }

  // tail: [h_final | c_final]
  const size_t tail = (size_t)T_DIM * B_DIM * H_DIM;
  out[tail + (size_t)bmine * 1024 + jmine] = hv;
  out[tail + (size_t)B_DIM * H_DIM + (size_t)bmine * 1024 + jmine] = creg;
}

// ===========================================================================
extern "C" void kernel_launch(void* const* d_in, const int* in_sizes, int n_in,
                              void* d_out, int out_size, void* d_ws, size_t ws_size,
                              hipStream_t stream) {
  const float* x  = (const float*)d_in[0];
  const float* Wx = (const float*)d_in[1];
  const float* Wh = (const float*)d_in[2];
  const float* bh = (const float*)d_in[3];
  float* out = (float*)d_out;

  const size_t xg_bytes = (size_t)T_DIM * B_DIM * G_DIM * 2;   // 256 MiB
  const size_t wh_bytes = (size_t)G_DIM * H_DIM * 2;           // 8 MiB
  const size_t hb_bytes = (size_t)B_DIM * H_DIM * 2;           // 128 KiB
  char* ws = (char*)d_ws;

  ushort_t* xg  = (ushort_t*)ws;
  ushort_t* Whb = (ushort_t*)(ws + xg_bytes);
  ushort_t* hb0 = (ushort_t*)(ws + xg_bytes + wh_bytes);
  ushort_t* hb1 = (ushort_t*)(ws + xg_bytes + wh_bytes + hb_bytes);
  int*      bar = (int*)(ws + xg_bytes + wh_bytes + 2 * hb_bytes);

  reset_bar_kernel<<<(T_DIM * 4 * BAR_STRIDE) / 256, 256, 0, stream>>>(bar);
  convert_bf16_kernel<<<(G_DIM * H_DIM / 8 + 255) / 256, 256, 0, stream>>>(
      Wh, Whb, G_DIM * H_DIM / 8);
  xg_gemm_mfma<<<dim3(T_DIM * B_DIM / 128, G_DIM / 128), 256, 0, stream>>>(
      x, Wx, bh, xg);
  lstm_persistent<<<NBLK, 256, 147456, stream>>>(xg, Whb, hb0, hb1, bar, out);
}

// Round 9
// 2651.246 us; speedup vs baseline: 4.1547x; 1.3616x over previous
//
#include <hip/hip_runtime.h>
#include <cstddef>
#include <cstdint>

// LSTM T=512 B=64 D=1024 H=1024.
//   Phase 1: convert x,Wx,Wh -> bf16; xg = x @ Wx^T + bh via MFMA GEMM with
//            global_load_lds(16B) staging (inverse-swizzled source, swizzled
//            ds_read) + XCD-swizzled flat grid.  Fallback (ws too small):
//            round-8 reg-staged GEMM.
//   Phase 2: ONE persistent kernel, 256 blocks x 4 waves (k-split), 512 steps.
//            h exchanged via sc0sc1 write-through stores + L2-bypassing agent
//            loads. Sync: PER-PRODUCER monotonic flags (64B-padded), wave-
//            parallel poll (lane L polls producer L), single uncontended flag
//            store per block per step. No central counter.
// d_out = [outputs(T,B,H) | h(B,H) | c(B,H)] f32.

#define T_DIM 512
#define B_DIM 64
#define H_DIM 1024
#define G_DIM 4096
#define NBLK 256
#define QBLK 64        // blocks per batch-quarter (flag group size)
#define BAR_STRIDE 16  // ints; one 64B line per flag slot

typedef short short8 __attribute__((ext_vector_type(8)));
typedef float f32x4 __attribute__((ext_vector_type(4)));
typedef unsigned short ushort_t;

__device__ __forceinline__ ushort_t f2b(float f) {   // f32 -> bf16 RNE
  union { float f; unsigned u; } v; v.f = f;
  unsigned r = v.u + 0x7fffu + ((v.u >> 16) & 1u);
  return (ushort_t)(r >> 16);
}
__device__ __forceinline__ float b2f(ushort_t u) {
  union { unsigned u; float f; } v; v.u = ((unsigned)u) << 16;
  return v.f;
}
__device__ __forceinline__ float sigmoidf_(float x) { return 1.0f / (1.0f + __expf(-x)); }

__device__ __forceinline__ void gload_lds16(const ushort_t* g, ushort_t* l) {
  __builtin_amdgcn_global_load_lds(
      (const __attribute__((address_space(1))) unsigned int*)g,
      (__attribute__((address_space(3))) unsigned int*)l, 16, 0, 0);
}

// ---------------------------------------------------------------------------
__global__ __launch_bounds__(256) void reset_flags_kernel(int* __restrict__ flg) {
  int i = blockIdx.x * 256 + threadIdx.x;
  if (i < NBLK * BAR_STRIDE) flg[i] = 0;
}

// convert f32 -> bf16, 8 elems/thread
__global__ __launch_bounds__(256) void convert_bf16_kernel(
    const float* __restrict__ src, ushort_t* __restrict__ dst, int n8) {
  int i = blockIdx.x * 256 + threadIdx.x;
  if (i >= n8) return;
  float4 v0 = *(const float4*)&src[(size_t)i * 8];
  float4 v1 = *(const float4*)&src[(size_t)i * 8 + 4];
  ushort_t p[8] = {f2b(v0.x), f2b(v0.y), f2b(v0.z), f2b(v0.w),
                   f2b(v1.x), f2b(v1.y), f2b(v1.z), f2b(v1.w)};
  *(short8*)&dst[(size_t)i * 8] = *(const short8*)p;
}

// ---------------------------------------------------------------------------
// NEW GEMM: bf16 inputs, global_load_lds(16B) staging.
// C[m][n] = bf16(sum_k A[m][k]*B[n][k] + bh[n]); M=32768 N=4096 K=1024.
// 128x128 tile, 4 waves (2x2), BK=64. LDS linear [128][64] bf16; the XOR
// swizzle (byte ^= (row&7)<<4) is realized by inverse-swizzling the per-lane
// GLOBAL source chunk: c_src = chunk ^ (row&7)  (rule #21: linear dest +
// inverse-swz source + swz read).
__global__ __launch_bounds__(256) void xg_gemm_lds(
    const ushort_t* __restrict__ Ab,   // x  bf16 [32768][1024]
    const ushort_t* __restrict__ Bb,   // Wx bf16 [4096][1024]
    const float* __restrict__ bh,      // [4096] f32
    ushort_t* __restrict__ C) {        // xg bf16 [32768][4096]
  __shared__ ushort_t As[128 * 64];
  __shared__ ushort_t Bs[128 * 64];
  const int tid = threadIdx.x;
  const int lane = tid & 63;
  const int w = tid >> 6;
  const int wm = w >> 1, wn = w & 1;
  // XCD swizzle: 8192 blocks, nwg%8==0 -> bijective
  const int flat = (int)blockIdx.x;
  const int swz = (flat & 7) * 1024 + (flat >> 3);
  const size_t m0 = (size_t)(swz & 255) * 128;
  const int n0 = (swz >> 8) * 128;
  const int lr = lane & 15;
  const int lk = (lane >> 4) * 8;
  const int srow = lane >> 3;          // 0..7 row within 8-row group
  const int schk = lane & 7;           // 16B chunk 0..7

  f32x4 acc[4][4];
#pragma unroll
  for (int i = 0; i < 4; ++i)
#pragma unroll
    for (int j = 0; j < 4; ++j) acc[i][j] = 0.0f;

  for (int k0 = 0; k0 < 1024; k0 += 64) {
    __syncthreads();
#pragma unroll
    for (int i = 0; i < 4; ++i) {
      const int base_row = w * 32 + i * 8;      // wave-uniform
      const int row = base_row + srow;
      const int csrc = (schk ^ (row & 7)) * 8;  // inverse-swizzled src chunk
      gload_lds16(&Ab[(m0 + row) * 1024 + k0 + csrc], &As[base_row * 64]);
      gload_lds16(&Bb[(size_t)(n0 + row) * 1024 + k0 + csrc], &Bs[base_row * 64]);
    }
    __syncthreads();
#pragma unroll
    for (int kk = 0; kk < 64; kk += 32) {
      short8 af[4], bf[4];
#pragma unroll
      for (int mf = 0; mf < 4; ++mf) {
        const int row = wm * 64 + mf * 16 + lr;
        const int byte = (row * 128 + (kk + lk) * 2) ^ ((row & 7) << 4);
        af[mf] = *(const short8*)((const char*)As + byte);
      }
#pragma unroll
      for (int nf = 0; nf < 4; ++nf) {
        const int row = wn * 64 + nf * 16 + lr;
        const int byte = (row * 128 + (kk + lk) * 2) ^ ((row & 7) << 4);
        bf[nf] = *(const short8*)((const char*)Bs + byte);
      }
#pragma unroll
      for (int mf = 0; mf < 4; ++mf)
#pragma unroll
        for (int nf = 0; nf < 4; ++nf)
          acc[mf][nf] = __builtin_amdgcn_mfma_f32_16x16x32_bf16(
              af[mf], bf[nf], acc[mf][nf], 0, 0, 0);
    }
  }
#pragma unroll
  for (int nf = 0; nf < 4; ++nf) {
    const int col = n0 + wn * 64 + nf * 16 + lr;
    const float bias = bh[col];
#pragma unroll
    for (int mf = 0; mf < 4; ++mf) {
      const size_t row0 = m0 + wm * 64 + mf * 16 + (lane >> 4) * 4;
#pragma unroll
      for (int rr = 0; rr < 4; ++rr)
        C[(row0 + rr) * 4096 + col] = f2b(acc[mf][nf][rr] + bias);
    }
  }
}

// ---------------------------------------------------------------------------
// FALLBACK GEMM (round-8, f32 inputs reg-staged): used only if ws too small.
__global__ __launch_bounds__(256) void xg_gemm_mfma(
    const float* __restrict__ A, const float* __restrict__ Bw,
    const float* __restrict__ bh, ushort_t* __restrict__ C) {
  __shared__ ushort_t As[128 * 64];
  __shared__ ushort_t Bs[128 * 64];
  const int tid = threadIdx.x;
  const int lane = tid & 63;
  const int w = tid >> 6;
  const int wm = w >> 1, wn = w & 1;
  const size_t m0 = (size_t)blockIdx.x * 128;
  const int n0 = blockIdx.y * 128;
  const int r = tid >> 1;
  const int kb = (tid & 1) * 32;
  f32x4 acc[4][4];
#pragma unroll
  for (int i = 0; i < 4; ++i)
#pragma unroll
    for (int j = 0; j < 4; ++j) acc[i][j] = 0.0f;
  const int lr = lane & 15;
  const int lk = (lane >> 4) * 8;
  for (int k0 = 0; k0 < 1024; k0 += 64) {
    __syncthreads();
#pragma unroll
    for (int i = 0; i < 4; ++i) {
      const int kk = kb + i * 8;
      float4 a0 = *(const float4*)&A[(m0 + r) * 1024 + k0 + kk];
      float4 a1 = *(const float4*)&A[(m0 + r) * 1024 + k0 + kk + 4];
      ushort_t pa[8] = {f2b(a0.x), f2b(a0.y), f2b(a0.z), f2b(a0.w),
                        f2b(a1.x), f2b(a1.y), f2b(a1.z), f2b(a1.w)};
      float4 b0 = *(const float4*)&Bw[(size_t)(n0 + r) * 1024 + k0 + kk];
      float4 b1 = *(const float4*)&Bw[(size_t)(n0 + r) * 1024 + k0 + kk + 4];
      ushort_t pb[8] = {f2b(b0.x), f2b(b0.y), f2b(b0.z), f2b(b0.w),
                        f2b(b1.x), f2b(b1.y), f2b(b1.z), f2b(b1.w)};
      const int byte = (r * 128 + kk * 2) ^ ((r & 7) << 4);
      *(short8*)((char*)As + byte) = *(const short8*)pa;
      *(short8*)((char*)Bs + byte) = *(const short8*)pb;
    }
    __syncthreads();
#pragma unroll
    for (int kk = 0; kk < 64; kk += 32) {
      short8 af[4], bf[4];
#pragma unroll
      for (int mf = 0; mf < 4; ++mf) {
        const int row = wm * 64 + mf * 16 + lr;
        const int byte = (row * 128 + (kk + lk) * 2) ^ ((row & 7) << 4);
        af[mf] = *(const short8*)((const char*)As + byte);
      }
#pragma unroll
      for (int nf = 0; nf < 4; ++nf) {
        const int row = wn * 64 + nf * 16 + lr;
        const int byte = (row * 128 + (kk + lk) * 2) ^ ((row & 7) << 4);
        bf[nf] = *(const short8*)((const char*)Bs + byte);
      }
#pragma unroll
      for (int mf = 0; mf < 4; ++mf)
#pragma unroll
        for (int nf = 0; nf < 4; ++nf)
          acc[mf][nf] = __builtin_amdgcn_mfma_f32_16x16x32_bf16(
              af[mf], bf[nf], acc[mf][nf], 0, 0, 0);
    }
  }
#pragma unroll
  for (int nf = 0; nf < 4; ++nf) {
    const int col = n0 + wn * 64 + nf * 16 + lr;
    const float bias = bh[col];
#pragma unroll
    for (int mf = 0; mf < 4; ++mf) {
      const size_t row0 = m0 + wm * 64 + mf * 16 + (lane >> 4) * 4;
#pragma unroll
      for (int rr = 0; rr < 4; ++rr)
        C[(row0 + rr) * 4096 + col] = f2b(acc[mf][nf][rr] + bias);
    }
  }
}

// ---------------------------------------------------------------------------
// Persistent recurrence, 4-wave k-split, per-producer flag sync.
// Block b: j0=(b>>2)*16, w=b&3. Wave v handles ks in [8v, 8v+8).
// Flags: flg[(w*64 + jblk)*BAR_STRIDE] = number of steps block (jblk,w) has
// completed (monotonic; zeroed each launch). Consumer at step t waits until
// all 64 same-w producers show >= t (wave-parallel: lane L polls producer L).
__global__ __launch_bounds__(256) void lstm_persistent(
    const ushort_t* __restrict__ xg,   // [T*64][4096] bf16 (bias folded)
    const ushort_t* __restrict__ Whb,  // [4096][1024] bf16
    ushort_t* __restrict__ hb0,        // [64][1024] bf16 ping
    ushort_t* __restrict__ hb1,        // [64][1024] bf16 pong
    int* __restrict__ flg,             // [NBLK*BAR_STRIDE] flags (zeroed)
    float* __restrict__ out) {         // [T][64][1024] f32 + tail
  extern __shared__ char smem[];
  ushort_t* Wlds = (ushort_t*)smem;            // 128 KiB, XOR-swizzled
  float* accs = (float*)(smem + 131072);       // 16 KiB reduce buffer
  const int tid = threadIdx.x;
  const int lane = tid & 63;
  const int v = tid >> 6;              // wave id = k-slice
  const int bid = (int)blockIdx.x;
  const int j0 = (bid >> 2) * 16;
  const int w  = bid & 3;
  const int lr = lane & 15;
  const int lq = lane >> 4;            // 0..3

  const int bmine = w * 16 + v * 4 + lq;   // epilogue-owned element
  const int jmine = j0 + lr;
  const int* fpoll = &flg[(w * 64 + lane) * BAR_STRIDE];
  int* fmine = &flg[(w * 64 + (bid >> 2)) * BAR_STRIDE];

  // one-time: stage this block's Wh slice into LDS (swizzled), 256 threads
  for (int e = tid; e < 8192; e += 256) {
    const int r  = e >> 7;             // LDS row 0..63 (= gate*16 + jj)
    const int ch = e & 127;            // 16B chunk within row
    const int gr = (r >> 4) * 1024 + j0 + (r & 15);
    short8 val = *(const short8*)(Whb + (size_t)gr * 1024 + ch * 8);
    const int byte = (r * 2048 + ch * 16) ^ ((r & 7) << 4);
    *(short8*)((char*)Wlds + byte) = val;
  }
  __syncthreads();

  float creg = 0.f;
  float hv = 0.f;

  for (int t = 0; t < T_DIM; ++t) {
    // prefetch this lane's xg (independent of h) before the poll
    const size_t xbase = ((size_t)t * 64 + bmine) * 4096 + jmine;
    float xgv[4];
#pragma unroll
    for (int g = 0; g < 4; ++g) xgv[g] = b2f(xg[xbase + (size_t)g * 1024]);

    f32x4 acc[4];
#pragma unroll
    for (int g = 0; g < 4; ++g) acc[g] = 0.f;

    if (t > 0) {
      // wave-parallel flag poll: lane L watches producer L of this quarter
      int fv;
      do {
        fv = __hip_atomic_load(fpoll, __ATOMIC_RELAXED,
                               __HIP_MEMORY_SCOPE_AGENT);
      } while (!__all(fv >= t));
      asm volatile("" ::: "memory");   // keep h loads after the poll

      // h loads: wave v covers ks in [8v, 8v+8); k-step = 32 bf16 = 8 u64
      const ushort_t* hprev = (t & 1) ? hb0 : hb1;
      const unsigned long long* hrow = (const unsigned long long*)(
          hprev + (size_t)(w * 16 + lr) * 1024 + v * 256 + lq * 8);
      short8 af[8];
#pragma unroll
      for (int i = 0; i < 8; ++i) {
        union { unsigned long long u[2]; short8 s; } av;
        av.u[0] = __hip_atomic_load(hrow + i * 8, __ATOMIC_RELAXED,
                                    __HIP_MEMORY_SCOPE_AGENT);
        av.u[1] = __hip_atomic_load(hrow + i * 8 + 1, __ATOMIC_RELAXED,
                                    __HIP_MEMORY_SCOPE_AGENT);
        af[i] = av.s;
      }
#pragma unroll
      for (int i = 0; i < 8; ++i) {
        const int ksg = v * 8 + i;
#pragma unroll
        for (int g = 0; g < 4; ++g) {
          const int row = g * 16 + lr;
          const int byte = (row * 2048 + ksg * 64 + lq * 16) ^ ((row & 7) << 4);
          short8 bfrag = *(const short8*)((const char*)Wlds + byte);
          acc[g] = __builtin_amdgcn_mfma_f32_16x16x32_bf16(af[i], bfrag,
                                                           acc[g], 0, 0, 0);
        }
      }
    }

    // write partials to LDS: [(v*4+g)*64 + lane] * f32x4
#pragma unroll
    for (int g = 0; g < 4; ++g)
      *(f32x4*)&accs[((v * 4 + g) * 64 + lane) * 4] = acc[g];
    __syncthreads();  // sync2

    // epilogue: reduce 4 partials per gate for my (bmine, jmine)
    float gv[4];
#pragma unroll
    for (int g = 0; g < 4; ++g) {
      float s = xgv[g];
#pragma unroll
      for (int v2 = 0; v2 < 4; ++v2)
        s += accs[((v2 * 4 + g) * 64 + v * 16 + lr) * 4 + lq];
      gv[g] = s;
    }
    const float ig = sigmoidf_(gv[0]);
    const float fg = sigmoidf_(gv[1]);
    const float gg = tanhf(gv[2]);
    const float og = sigmoidf_(gv[3]);
    const float cn = fmaf(fg, creg, ig * gg);
    creg = cn;
    hv = og * tanhf(cn);

    // h store (write-through), block-wide drain, publish flag
    ushort_t* hcur = (t & 1) ? hb1 : hb0;
    __hip_atomic_store(&hcur[(size_t)bmine * 1024 + jmine], f2b(hv),
                       __ATOMIC_RELAXED, __HIP_MEMORY_SCOPE_AGENT);
    asm volatile("s_waitcnt vmcnt(0)" ::: "memory");
    __syncthreads();  // sync3: all waves' h stores drained

    if (t < T_DIM - 1 && tid == 0)
      __hip_atomic_store(fmine, t + 1, __ATOMIC_RELAXED,
                         __HIP_MEMORY_SCOPE_AGENT);

    // out[] store after publish -- off the inter-block critical path
    out[((size_t)t * 64 + bmine) * 1024 + jmine] = hv;
  }

  // tail: [h_final | c_final]
  const size_t tail = (size_t)T_DIM * B_DIM * H_DIM;
  out[tail + (size_t)bmine * 1024 + jmine] = hv;
  out[tail + (size_t)B_DIM * H_DIM + (size_t)bmine * 1024 + jmine] = creg;
}

// ===========================================================================
extern "C" void kernel_launch(void* const* d_in, const int* in_sizes, int n_in,
                              void* d_out, int out_size, void* d_ws, size_t ws_size,
                              hipStream_t stream) {
  const float* x  = (const float*)d_in[0];
  const float* Wx = (const float*)d_in[1];
  const float* Wh = (const float*)d_in[2];
  const float* bh = (const float*)d_in[3];
  float* out = (float*)d_out;

  const size_t xg_bytes  = (size_t)T_DIM * B_DIM * G_DIM * 2;  // 256 MiB
  const size_t wh_bytes  = (size_t)G_DIM * H_DIM * 2;          // 8 MiB
  const size_t hb_bytes  = (size_t)B_DIM * H_DIM * 2;          // 128 KiB
  const size_t flg_bytes = (size_t)NBLK * BAR_STRIDE * 4;      // 16 KiB
  const size_t x_bytes   = (size_t)T_DIM * B_DIM * H_DIM * 2;  // 64 MiB
  const size_t wx_bytes  = (size_t)G_DIM * H_DIM * 2;          // 8 MiB
  char* ws = (char*)d_ws;

  size_t off = 0;
  ushort_t* xg  = (ushort_t*)(ws + off); off += xg_bytes;
  ushort_t* Whb = (ushort_t*)(ws + off); off += wh_bytes;
  ushort_t* hb0 = (ushort_t*)(ws + off); off += hb_bytes;
  ushort_t* hb1 = (ushort_t*)(ws + off); off += hb_bytes;
  int*      flg = (int*)(ws + off);      off += flg_bytes;
  ushort_t* xb  = (ushort_t*)(ws + off); off += x_bytes;
  ushort_t* wxb = (ushort_t*)(ws + off); off += wx_bytes;
  const size_t need_full = off;

  reset_flags_kernel<<<(NBLK * BAR_STRIDE + 255) / 256, 256, 0, stream>>>(flg);
  convert_bf16_kernel<<<G_DIM * H_DIM / 8 / 256, 256, 0, stream>>>(
      Wh, Whb, G_DIM * H_DIM / 8);

  if (ws_size >= need_full) {
    convert_bf16_kernel<<<T_DIM * B_DIM * H_DIM / 8 / 256, 256, 0, stream>>>(
        x, xb, T_DIM * B_DIM * H_DIM / 8);
    convert_bf16_kernel<<<G_DIM * H_DIM / 8 / 256, 256, 0, stream>>>(
        Wx, wxb, G_DIM * H_DIM / 8);
    xg_gemm_lds<<<8192, 256, 0, stream>>>(xb, wxb, bh, xg);
  } else {
    xg_gemm_mfma<<<dim3(T_DIM * B_DIM / 128, G_DIM / 128), 256, 0, stream>>>(
        x, Wx, bh, xg);
  }
  lstm_persistent<<<NBLK, 256, 147456, stream>>>(xg, Whb, hb0, hb1, flg, out);
}